// Round 5
// baseline (64888.324 us; speedup 1.0000x reference)
//
#include <hip/hip_runtime.h>
#include <stdint.h>

typedef unsigned long long u64;
typedef uint32_t u32;

#define NPTS 50000
#define MCL  8334          // ceil(50000/6)
#define NITER 8333         // FPS steps after seed
#define OUTC 128
#define PTT  49            // points per FPS thread (1024*49 = 50176 >= NPTS)
#define KCH 4              // knn N-chunks
#define CPTS 12500         // points per chunk
#define KTILE 250
#define NTILE 50
#define QBLK 33            // ceil(MCL/256)
#define RB 782             // ceil(NPTS/64) row-blocks for stats
#define NCELL 4096         // 16^3 Morton cells

// ---- ws byte offsets (total ~4.84 MB; proven budget >= 6.17 MB) ----
#define WS_IDS   0u            // 8448 i32
#define WS_BBOX  33792u        // 8 f32 (min xyz, scale xyz)
#define WS_POSF4 33824u        // 50000 float4 (orig order, w=||p||^2)  -> for KNN
#define WS_SPOS  833824u       // 50176 float4 (sorted, w=orig idx bits) -> for FPS
#define WS_CAND  1636640u      // 8334*32 u64
#define WS_COL   3770144u      // 8334*8 i32
#define WS_PSUM  4036832u      // 782*128 f32
#define WS_PSQ   4437216u      // 782*128 f32
#define WS_AB    4837600u      // alpha[128], beta[128]
#define WS_TOTAL 4838624u

#define OUT_POS   (MCL * OUTC)            // 1066752
#define OUT_BATCH (OUT_POS + MCL * 3)     // 1091754

// pack pos + precomputed ||p||^2 (exact np order: (x*x+y*y)+z*z, no FMA)
__global__ void k_prep(const float* __restrict__ pos, float4* __restrict__ posf4) {
    int i = blockIdx.x * blockDim.x + threadIdx.x;
    if (i < NPTS) {
        float x = pos[3 * i], y = pos[3 * i + 1], z = pos[3 * i + 2];
        float pp = __fadd_rn(__fadd_rn(__fmul_rn(x, x), __fmul_rn(y, y)), __fmul_rn(z, z));
        posf4[i] = make_float4(x, y, z, pp);
    }
}

// global bbox -> min + scale (perf-only; any grouping is exact)
__global__ void __launch_bounds__(1024) k_bbox(const float* __restrict__ pos,
                                               float* __restrict__ bbox) {
    __shared__ float red[16][6];
    const int tid = threadIdx.x, lane = tid & 63, wid = tid >> 6;
    float mnx = 3.4e38f, mny = 3.4e38f, mnz = 3.4e38f;
    float mxx = -3.4e38f, mxy = -3.4e38f, mxz = -3.4e38f;
    for (int i = tid; i < NPTS; i += 1024) {
        float x = pos[3 * i], y = pos[3 * i + 1], z = pos[3 * i + 2];
        mnx = fminf(mnx, x); mxx = fmaxf(mxx, x);
        mny = fminf(mny, y); mxy = fmaxf(mxy, y);
        mnz = fminf(mnz, z); mxz = fmaxf(mxz, z);
    }
    #pragma unroll
    for (int o = 32; o >= 1; o >>= 1) {
        mnx = fminf(mnx, __shfl_xor(mnx, o)); mxx = fmaxf(mxx, __shfl_xor(mxx, o));
        mny = fminf(mny, __shfl_xor(mny, o)); mxy = fmaxf(mxy, __shfl_xor(mxy, o));
        mnz = fminf(mnz, __shfl_xor(mnz, o)); mxz = fmaxf(mxz, __shfl_xor(mxz, o));
    }
    if (lane == 0) {
        red[wid][0] = mnx; red[wid][1] = mny; red[wid][2] = mnz;
        red[wid][3] = mxx; red[wid][4] = mxy; red[wid][5] = mxz;
    }
    __syncthreads();
    if (tid == 0) {
        for (int w2 = 1; w2 < 16; ++w2) {
            red[0][0] = fminf(red[0][0], red[w2][0]);
            red[0][1] = fminf(red[0][1], red[w2][1]);
            red[0][2] = fminf(red[0][2], red[w2][2]);
            red[0][3] = fmaxf(red[0][3], red[w2][3]);
            red[0][4] = fmaxf(red[0][4], red[w2][4]);
            red[0][5] = fmaxf(red[0][5], red[w2][5]);
        }
        bbox[0] = red[0][0]; bbox[1] = red[0][1]; bbox[2] = red[0][2];
        bbox[3] = 16.0f / (fmaxf(red[0][3] - red[0][0], 1e-20f) * 1.000001f);
        bbox[4] = 16.0f / (fmaxf(red[0][4] - red[0][1], 1e-20f) * 1.000001f);
        bbox[5] = 16.0f / (fmaxf(red[0][5] - red[0][2], 1e-20f) * 1.000001f);
    }
}

__device__ __forceinline__ u32 mort(int cx, int cy, int cz) {
    u32 m = 0;
    #pragma unroll
    for (int b = 0; b < 4; ++b)
        m |= (((cx >> b) & 1) << (3 * b)) | (((cy >> b) & 1) << (3 * b + 1)) |
             (((cz >> b) & 1) << (3 * b + 2));
    return m;
}

__device__ __forceinline__ u32 cell_of(float x, float y, float z, const float* bb) {
    int cx = (int)((x - bb[0]) * bb[3]);
    int cy = (int)((y - bb[1]) * bb[4]);
    int cz = (int)((z - bb[2]) * bb[5]);
    cx = min(15, max(0, cx)); cy = min(15, max(0, cy)); cz = min(15, max(0, cz));
    return mort(cx, cy, cz);
}

// single-block Morton bucket sort: hist -> scan -> scatter (w = orig idx bits)
__global__ void __launch_bounds__(1024) k_sort(const float* __restrict__ pos,
                                               const float* __restrict__ bbox,
                                               float4* __restrict__ spos) {
    __shared__ u32 hist[NCELL];
    __shared__ u32 wsum[16];
    const int tid = threadIdx.x, lane = tid & 63, wid = tid >> 6;
    float bb[6];
    #pragma unroll
    for (int j = 0; j < 6; ++j) bb[j] = bbox[j];
    for (int i = tid; i < NCELL; i += 1024) hist[i] = 0u;
    __syncthreads();
    for (int i = tid; i < NPTS; i += 1024) {
        float x = pos[3 * i], y = pos[3 * i + 1], z = pos[3 * i + 2];
        atomicAdd(&hist[cell_of(x, y, z, bb)], 1u);
    }
    __syncthreads();
    u32 h0 = hist[tid * 4], h1 = hist[tid * 4 + 1], h2 = hist[tid * 4 + 2], h3 = hist[tid * 4 + 3];
    u32 ts = h0 + h1 + h2 + h3;
    u32 sc = ts;
    #pragma unroll
    for (int o = 1; o < 64; o <<= 1) { u32 n = __shfl_up(sc, o); if (lane >= o) sc += n; }
    if (lane == 63) wsum[wid] = sc;
    __syncthreads();
    u32 woff = 0;
    for (int w2 = 0; w2 < wid; ++w2) woff += wsum[w2];
    u32 excl = woff + sc - ts;
    hist[tid * 4 + 0] = excl;
    hist[tid * 4 + 1] = excl + h0;
    hist[tid * 4 + 2] = excl + h0 + h1;
    hist[tid * 4 + 3] = excl + h0 + h1 + h2;
    __syncthreads();
    for (int i = tid; i < NPTS; i += 1024) {
        float x = pos[3 * i], y = pos[3 * i + 1], z = pos[3 * i + 2];
        u32 dst = atomicAdd(&hist[cell_of(x, y, z, bb)], 1u);
        spos[dst] = make_float4(x, y, z, __uint_as_float((u32)i));
    }
}

// Exact FPS, single persistent block. Per thread: 49 sorted points, static bbox,
// md[] in regs, cached best key. Skip chunk when LB^2*(1-1e-6) >= max(md)
// (conservative under fp error => no md changes => cached key exact).
// key = (md_bits<<32) | (0xFFFF - orig_idx): u64-max == first-index argmax.
// tmax starts at the BIG sentinel (1e10) so iteration 0 always scans and
// establishes a valid cached key (lb is O(10) << 1e10).
__global__ void __launch_bounds__(1024) k_fps2(const float4* __restrict__ spos,
                                               const float4* __restrict__ posf4,
                                               const float* __restrict__ pos,
                                               int* __restrict__ ids) {
    const int tid = threadIdx.x, lane = tid & 63, wid = tid >> 6;
    const int base = tid * PTT;
    __shared__ u64 wred[2][16];
    float md[PTT];
    int nv = NPTS - base; nv = nv < 0 ? 0 : (nv > PTT ? PTT : nv);
    float bxn = 3.4e38f, byn = 3.4e38f, bzn = 3.4e38f;
    float bxm = -3.4e38f, bym = -3.4e38f, bzm = -3.4e38f;
    #pragma unroll
    for (int i = 0; i < PTT; ++i) {
        md[i] = 1e10f;
        if (i < nv) {
            float4 s = spos[base + i];
            bxn = fminf(bxn, s.x); bxm = fmaxf(bxm, s.x);
            byn = fminf(byn, s.y); bym = fmaxf(bym, s.y);
            bzn = fminf(bzn, s.z); bzm = fmaxf(bzm, s.z);
        }
    }
    u64 tkey = 0ull;
    float tmax = 1e10f;                 // md[] all start at BIG -> force first scan
    float cx = pos[0], cy = pos[1], cz = pos[2];   // seed: original point 0
    if (tid == 0) ids[0] = 0;
    for (int it = 0; it < NITER; ++it) {
        float ddx = fmaxf(0.0f, fmaxf(bxn - cx, cx - bxm));
        float ddy = fmaxf(0.0f, fmaxf(byn - cy, cy - bym));
        float ddz = fmaxf(0.0f, fmaxf(bzn - cz, cz - bzm));
        float lb = (ddx * ddx + ddy * ddy + ddz * ddz) * 0.999999f;
        if (nv > 0 && lb < tmax) {
            u64 nk = 0ull;
            #pragma unroll
            for (int i = 0; i < PTT; ++i) {
                if (i < nv) {
                    float4 s = spos[base + i];
                    // exact np arithmetic: rn sub/mul/add, no contraction
                    float dx = __fsub_rn(s.x, cx), dy = __fsub_rn(s.y, cy), dz = __fsub_rn(s.z, cz);
                    float d = __fadd_rn(__fadd_rn(__fmul_rn(dx, dx), __fmul_rn(dy, dy)),
                                        __fmul_rn(dz, dz));
                    float m = fminf(md[i], d);
                    md[i] = m;
                    u64 k = ((u64)__float_as_uint(m) << 32) |
                            (u64)(0xFFFFu - (u32)__float_as_uint(s.w));
                    if (k > nk) nk = k;
                }
            }
            tkey = nk;
            tmax = __uint_as_float((u32)(nk >> 32));
        }
        u64 k = tkey;
        #pragma unroll
        for (int o = 32; o >= 1; o >>= 1) { u64 ot = __shfl_xor(k, o); if (ot > k) k = ot; }
        if (lane == 0) wred[it & 1][wid] = k;
        __syncthreads();
        u64 v = (lane < 16) ? wred[it & 1][lane] : 0ull;
        #pragma unroll
        for (int o = 8; o >= 1; o >>= 1) { u64 ot = __shfl_xor(v, o); if (ot > v) v = ot; }
        v = __shfl(v, 0);
        int orig = 0xFFFF - (int)(v & 0xFFFFull);
        if (tid == 0) ids[it + 1] = orig;
        float4 c = posf4[orig];   // uniform broadcast load
        cx = c.x; cy = c.y; cz = c.z;
    }
}

// sub_pos + sub_batch outputs
__global__ void k_subs(const float* __restrict__ pos, const int* __restrict__ batch,
                       const int* __restrict__ ids, float* __restrict__ out) {
    int m = blockIdx.x * blockDim.x + threadIdx.x;
    if (m < MCL) {
        int id = ids[m];
        out[OUT_POS + m * 3 + 0] = pos[id * 3 + 0];
        out[OUT_POS + m * 3 + 1] = pos[id * 3 + 1];
        out[OUT_POS + m * 3 + 2] = pos[id * 3 + 2];
        out[OUT_BATCH + m] = (float)batch[id];  // zeros in this problem
    }
}

__device__ __forceinline__ u32 f2sort(float d) {
    u32 u = __float_as_uint(d);
    return (u & 0x80000000u) ? ~u : (u | 0x80000000u);
}

// per-(query-block, chunk) partial top-8 by (d, idx) lex key
__global__ void __launch_bounds__(256) k_knn(const float4* __restrict__ posf4,
                                             const int* __restrict__ ids,
                                             u64* __restrict__ cand) {
    __shared__ float4 tile[KTILE];
    const int bid = blockIdx.x, tid = threadIdx.x;
    const int qb = bid % QBLK, chunk = bid / QBLK;
    const int q = qb * 256 + tid;
    const bool act = q < MCL;
    float qx = 0.f, qy = 0.f, qz = 0.f, qq = 0.f;
    if (act) { float4 p = posf4[ids[q]]; qx = p.x; qy = p.y; qz = p.z; qq = p.w; }
    u64 r[8];
    #pragma unroll
    for (int j = 0; j < 8; ++j) r[j] = ~0ull;
    const int base0 = chunk * CPTS;
    for (int t = 0; t < NTILE; ++t) {
        __syncthreads();
        if (tid < KTILE) tile[tid] = posf4[base0 + t * KTILE + tid];
        __syncthreads();
        if (act) {
            for (int p = 0; p < KTILE; ++p) {
                float4 f = tile[p];
                // BLAS sgemm K=3 rounding: c=rn(qx*px); c=fma(qy,py,c); c=fma(qz,pz,c)
                float c = __fmul_rn(qx, f.x);
                c = fmaf(qy, f.y, c);
                c = fmaf(qz, f.z, c);
                float d = __fadd_rn(__fsub_rn(qq, __fmul_rn(2.0f, c)), f.w);
                u64 key = ((u64)f2sort(d) << 32) | (u32)(base0 + t * KTILE + p);
                if (key < r[7]) {
                    r[7] = key;
                    #pragma unroll
                    for (int jj = 7; jj >= 1; --jj) {
                        if (r[jj] < r[jj - 1]) { u64 tk = r[jj]; r[jj] = r[jj - 1]; r[jj - 1] = tk; }
                    }
                }
            }
        }
    }
    if (act) {
        #pragma unroll
        for (int j = 0; j < 8; ++j) cand[(size_t)q * 32 + chunk * 8 + j] = r[j];
    }
}

__global__ void k_merge(const u64* __restrict__ cand, int* __restrict__ col) {
    int q = blockIdx.x * blockDim.x + threadIdx.x;
    if (q >= MCL) return;
    u64 r[8];
    #pragma unroll
    for (int j = 0; j < 8; ++j) r[j] = ~0ull;
    for (int k = 0; k < 32; ++k) {
        u64 key = cand[(size_t)q * 32 + k];
        if (key < r[7]) {
            r[7] = key;
            #pragma unroll
            for (int jj = 7; jj >= 1; --jj) {
                if (r[jj] < r[jj - 1]) { u64 tk = r[jj]; r[jj] = r[jj - 1]; r[jj - 1] = tk; }
            }
        }
    }
    #pragma unroll
    for (int j = 0; j < 8; ++j) col[q * 8 + j] = (int)(r[j] & 0xFFFFFFFFull);
}

// Linear(64->128) per-channel sum / sumsq partials (64 rows per block)
__global__ void __launch_bounds__(256) k_linstats(const float* __restrict__ x,
                                                  const float* __restrict__ w,
                                                  const float* __restrict__ b,
                                                  float* __restrict__ psum,
                                                  float* __restrict__ psq) {
    __shared__ float xs[64 * 65];
    __shared__ float ws[128 * 65];
    const int bid = blockIdx.x, tid = threadIdx.x;
    const int row0 = bid * 64;
    for (int idx = tid; idx < 64 * 64; idx += 256) {
        int r = idx >> 6, j = idx & 63;
        int gr = row0 + r;
        xs[r * 65 + j] = (gr < NPTS) ? x[gr * 64 + j] : 0.0f;
    }
    for (int idx = tid; idx < 128 * 64; idx += 256) {
        int c = idx >> 6, j = idx & 63;
        ws[c * 65 + j] = w[idx];
    }
    __syncthreads();
    const int ch = tid & 127, grp = tid >> 7;
    const float lb = b[ch];
    float s = 0.f, sq = 0.f;
    for (int rr = 0; rr < 32; ++rr) {
        int r = grp * 32 + rr;
        float acc = lb;
        #pragma unroll 8
        for (int j = 0; j < 64; ++j) acc = fmaf(xs[r * 65 + j], ws[ch * 65 + j], acc);
        if (row0 + r < NPTS) { s += acc; sq = fmaf(acc, acc, sq); }
    }
    __syncthreads();
    float* red = xs;  // reuse
    red[grp * 128 + ch] = s;
    red[256 + grp * 128 + ch] = sq;
    __syncthreads();
    if (grp == 0) {
        psum[bid * 128 + ch] = red[ch] + red[128 + ch];
        psq[bid * 128 + ch] = red[256 + ch] + red[256 + 128 + ch];
    }
}

// mean/var -> per-channel affine (alpha, beta); folds GraphNorm
__global__ void k_finalize(const float* __restrict__ psum, const float* __restrict__ psq,
                           const float* __restrict__ gnw, const float* __restrict__ gnb,
                           const float* __restrict__ gms, float* __restrict__ ab) {
    int ch = threadIdx.x;  // 128 threads
    float s = 0.f, q = 0.f;
    for (int bk = 0; bk < RB; ++bk) { s += psum[bk * 128 + ch]; q += psq[bk * 128 + ch]; }
    float m = s / (float)NPTS;
    float e2 = q / (float)NPTS;
    float msc = gms[ch];
    float mm = msc * m;
    float var = e2 - 2.0f * mm * m + mm * mm;
    float inv = rsqrtf(var + 1e-5f);
    float a = inv * gnw[ch];
    ab[ch] = a;
    ab[128 + ch] = gnb[ch] - mm * a;
}

// recompute h rows for the 8 neighbors, max/min, affine+relu, write out
__global__ void __launch_bounds__(128) k_gather(const float* __restrict__ x,
                                                const float* __restrict__ w,
                                                const float* __restrict__ b,
                                                const int* __restrict__ col,
                                                const float* __restrict__ ab,
                                                float* __restrict__ out) {
    __shared__ float xs[8 * 64];
    __shared__ float ws[128 * 65];
    __shared__ int cl[8];
    const int m = blockIdx.x, tid = threadIdx.x;
    if (tid < 8) cl[tid] = col[m * 8 + tid];
    __syncthreads();
    for (int idx = tid; idx < 512; idx += 128) {
        int r = idx >> 6, j = idx & 63;
        xs[idx] = x[cl[r] * 64 + j];
    }
    for (int idx = tid; idx < 128 * 64; idx += 128) {
        int c = idx >> 6, j = idx & 63;
        ws[c * 65 + j] = w[idx];
    }
    __syncthreads();
    const int ch = tid;
    const float lb = b[ch];
    float hmax = -3.402823466e38f, hmin = 3.402823466e38f;
    #pragma unroll
    for (int r = 0; r < 8; ++r) {
        float acc = lb;
        #pragma unroll 8
        for (int j = 0; j < 64; ++j) acc = fmaf(xs[r * 64 + j], ws[ch * 65 + j], acc);
        hmax = fmaxf(hmax, acc);
        hmin = fminf(hmin, acc);
    }
    float a = ab[ch], be = ab[128 + ch];
    float v = (a >= 0.0f) ? hmax : hmin;   // max/affine commute per sign
    out[m * OUTC + ch] = fmaxf(0.0f, fmaf(a, v, be));
}

extern "C" void kernel_launch(void* const* d_in, const int* in_sizes, int n_in,
                              void* d_out, int out_size, void* d_ws, size_t ws_size,
                              hipStream_t stream) {
    const float* x     = (const float*)d_in[0];
    const float* pos   = (const float*)d_in[1];
    const int*   batch = (const int*)d_in[2];
    const float* lin_w = (const float*)d_in[3];
    const float* lin_b = (const float*)d_in[4];
    const float* gnw   = (const float*)d_in[5];
    const float* gnb   = (const float*)d_in[6];
    const float* gms   = (const float*)d_in[7];
    float* out = (float*)d_out;

    if (ws_size < (size_t)WS_TOTAL) return;  // fail loudly via wrong output

    char* ws = (char*)d_ws;
    int*    ids   = (int*)(ws + WS_IDS);
    float*  bbox  = (float*)(ws + WS_BBOX);
    float4* posf4 = (float4*)(ws + WS_POSF4);
    float4* spos  = (float4*)(ws + WS_SPOS);
    u64*    cand  = (u64*)(ws + WS_CAND);
    int*    col   = (int*)(ws + WS_COL);
    float*  psum  = (float*)(ws + WS_PSUM);
    float*  psq   = (float*)(ws + WS_PSQ);
    float*  ab    = (float*)(ws + WS_AB);

    k_prep<<<196, 256, 0, stream>>>(pos, posf4);
    k_bbox<<<1, 1024, 0, stream>>>(pos, bbox);
    k_sort<<<1, 1024, 0, stream>>>(pos, bbox, spos);
    k_fps2<<<1, 1024, 0, stream>>>(spos, posf4, pos, ids);
    k_subs<<<QBLK, 256, 0, stream>>>(pos, batch, ids, out);
    k_knn<<<QBLK * KCH, 256, 0, stream>>>(posf4, ids, cand);
    k_merge<<<QBLK, 256, 0, stream>>>(cand, col);
    k_linstats<<<RB, 256, 0, stream>>>(x, lin_w, lin_b, psum, psq);
    k_finalize<<<1, 128, 0, stream>>>(psum, psq, gnw, gnb, gms, ab);
    k_gather<<<MCL, 128, 0, stream>>>(x, lin_w, lin_b, col, ab, out);
}

// Round 6
// 34100.632 us; speedup vs baseline: 1.9028x; 1.9028x over previous
//
#include <hip/hip_runtime.h>
#include <stdint.h>

typedef unsigned long long u64;
typedef uint32_t u32;

#define NPTS 50000
#define MCL  8334          // ceil(50000/6)
#define NITER 8333         // FPS steps after seed
#define OUTC 128
#define PTT  49            // points per FPS thread (1024*49 = 50176 >= NPTS)
#define NPAD (1024 * PTT)  // 50176
#define KCH 4              // knn N-chunks
#define CPTS 12500         // points per chunk
#define KTILE 250
#define NTILE 50
#define QBLK 33            // ceil(MCL/256)
#define RB 782             // ceil(NPTS/64) row-blocks for stats
#define NCELL 4096         // 16^3 Morton cells

// ---- ws byte offsets (total ~4.84 MB; proven budget >= 6.17 MB) ----
#define WS_IDS   0u            // 8448 i32
#define WS_BBOX  33792u        // 8 f32 (min xyz, scale xyz)
#define WS_POSF4 33824u        // 50000 float4 (orig order, w=||p||^2)  -> for KNN
#define WS_SPOS  833824u       // 50176 float4 (sorted, w=orig idx bits) -> for FPS
#define WS_CAND  1636640u      // 8334*32 u64
#define WS_COL   3770144u      // 8334*8 i32
#define WS_PSUM  4036832u      // 782*128 f32
#define WS_PSQ   4437216u      // 782*128 f32
#define WS_AB    4837600u      // alpha[128], beta[128]
#define WS_TOTAL 4838624u

#define OUT_POS   (MCL * OUTC)            // 1066752
#define OUT_BATCH (OUT_POS + MCL * 3)     // 1091754

// pack pos + precomputed ||p||^2 (exact np order: (x*x+y*y)+z*z, no FMA)
__global__ void k_prep(const float* __restrict__ pos, float4* __restrict__ posf4) {
    int i = blockIdx.x * blockDim.x + threadIdx.x;
    if (i < NPTS) {
        float x = pos[3 * i], y = pos[3 * i + 1], z = pos[3 * i + 2];
        float pp = __fadd_rn(__fadd_rn(__fmul_rn(x, x), __fmul_rn(y, y)), __fmul_rn(z, z));
        posf4[i] = make_float4(x, y, z, pp);
    }
}

// global bbox -> min + scale (perf-only; any grouping is exact)
__global__ void __launch_bounds__(1024) k_bbox(const float* __restrict__ pos,
                                               float* __restrict__ bbox) {
    __shared__ float red[16][6];
    const int tid = threadIdx.x, lane = tid & 63, wid = tid >> 6;
    float mnx = 3.4e38f, mny = 3.4e38f, mnz = 3.4e38f;
    float mxx = -3.4e38f, mxy = -3.4e38f, mxz = -3.4e38f;
    for (int i = tid; i < NPTS; i += 1024) {
        float x = pos[3 * i], y = pos[3 * i + 1], z = pos[3 * i + 2];
        mnx = fminf(mnx, x); mxx = fmaxf(mxx, x);
        mny = fminf(mny, y); mxy = fmaxf(mxy, y);
        mnz = fminf(mnz, z); mxz = fmaxf(mxz, z);
    }
    #pragma unroll
    for (int o = 32; o >= 1; o >>= 1) {
        mnx = fminf(mnx, __shfl_xor(mnx, o)); mxx = fmaxf(mxx, __shfl_xor(mxx, o));
        mny = fminf(mny, __shfl_xor(mny, o)); mxy = fmaxf(mxy, __shfl_xor(mxy, o));
        mnz = fminf(mnz, __shfl_xor(mnz, o)); mxz = fmaxf(mxz, __shfl_xor(mxz, o));
    }
    if (lane == 0) {
        red[wid][0] = mnx; red[wid][1] = mny; red[wid][2] = mnz;
        red[wid][3] = mxx; red[wid][4] = mxy; red[wid][5] = mxz;
    }
    __syncthreads();
    if (tid == 0) {
        for (int w2 = 1; w2 < 16; ++w2) {
            red[0][0] = fminf(red[0][0], red[w2][0]);
            red[0][1] = fminf(red[0][1], red[w2][1]);
            red[0][2] = fminf(red[0][2], red[w2][2]);
            red[0][3] = fmaxf(red[0][3], red[w2][3]);
            red[0][4] = fmaxf(red[0][4], red[w2][4]);
            red[0][5] = fmaxf(red[0][5], red[w2][5]);
        }
        bbox[0] = red[0][0]; bbox[1] = red[0][1]; bbox[2] = red[0][2];
        bbox[3] = 16.0f / (fmaxf(red[0][3] - red[0][0], 1e-20f) * 1.000001f);
        bbox[4] = 16.0f / (fmaxf(red[0][4] - red[0][1], 1e-20f) * 1.000001f);
        bbox[5] = 16.0f / (fmaxf(red[0][5] - red[0][2], 1e-20f) * 1.000001f);
    }
}

__device__ __forceinline__ u32 mort(int cx, int cy, int cz) {
    u32 m = 0;
    #pragma unroll
    for (int b = 0; b < 4; ++b)
        m |= (((cx >> b) & 1) << (3 * b)) | (((cy >> b) & 1) << (3 * b + 1)) |
             (((cz >> b) & 1) << (3 * b + 2));
    return m;
}

__device__ __forceinline__ u32 cell_of(float x, float y, float z, const float* bb) {
    int cx = (int)((x - bb[0]) * bb[3]);
    int cy = (int)((y - bb[1]) * bb[4]);
    int cz = (int)((z - bb[2]) * bb[5]);
    cx = min(15, max(0, cx)); cy = min(15, max(0, cy)); cz = min(15, max(0, cz));
    return mort(cx, cy, cz);
}

// single-block Morton bucket sort: hist -> scan -> scatter (w = orig idx bits).
// Pads [NPTS..NPAD) = clones of point 0 with idx sentinel 0xFFFF (inv16=0):
// they can never win the argmax (point 0 beats them on tie-break), and since
// point 0 is center 0 their md collapses to 0 at iter 0 (never inflate tmax).
__global__ void __launch_bounds__(1024) k_sort(const float* __restrict__ pos,
                                               const float* __restrict__ bbox,
                                               float4* __restrict__ spos) {
    __shared__ u32 hist[NCELL];
    __shared__ u32 wsum[16];
    const int tid = threadIdx.x, lane = tid & 63, wid = tid >> 6;
    float bb[6];
    #pragma unroll
    for (int j = 0; j < 6; ++j) bb[j] = bbox[j];
    float p0x = pos[0], p0y = pos[1], p0z = pos[2];
    for (int i = NPTS + tid; i < NPAD; i += 1024)
        spos[i] = make_float4(p0x, p0y, p0z, __uint_as_float(0xFFFFu));
    for (int i = tid; i < NCELL; i += 1024) hist[i] = 0u;
    __syncthreads();
    for (int i = tid; i < NPTS; i += 1024) {
        float x = pos[3 * i], y = pos[3 * i + 1], z = pos[3 * i + 2];
        atomicAdd(&hist[cell_of(x, y, z, bb)], 1u);
    }
    __syncthreads();
    u32 h0 = hist[tid * 4], h1 = hist[tid * 4 + 1], h2 = hist[tid * 4 + 2], h3 = hist[tid * 4 + 3];
    u32 ts = h0 + h1 + h2 + h3;
    u32 sc = ts;
    #pragma unroll
    for (int o = 1; o < 64; o <<= 1) { u32 n = __shfl_up(sc, o); if (lane >= o) sc += n; }
    if (lane == 63) wsum[wid] = sc;
    __syncthreads();
    u32 woff = 0;
    for (int w2 = 0; w2 < wid; ++w2) woff += wsum[w2];
    u32 excl = woff + sc - ts;
    hist[tid * 4 + 0] = excl;
    hist[tid * 4 + 1] = excl + h0;
    hist[tid * 4 + 2] = excl + h0 + h1;
    hist[tid * 4 + 3] = excl + h0 + h1 + h2;
    __syncthreads();
    for (int i = tid; i < NPTS; i += 1024) {
        float x = pos[3 * i], y = pos[3 * i + 1], z = pos[3 * i + 2];
        u32 dst = atomicAdd(&hist[cell_of(x, y, z, bb)], 1u);
        spos[dst] = make_float4(x, y, z, __uint_as_float((u32)i));
    }
}

// Exact FPS v3: single block, wave-0-only reduce, branch-free scan, md in VGPRs.
// Per iteration:
//   Phase A: per-thread bbox skip (lb*(1-1e-6) >= tmax => provably no md change);
//            active threads scan 49 pts (no conditionals), write key to LDS.
//   barrier; Phase B: wave 0 reads 1024 keys, max-reduce, lane0 publishes center.
//   barrier; all read center.
// key = (md_bits<<32)|(0xFFFF-idx): u64-max == first-index argmax (jnp.argmax).
__global__ void __launch_bounds__(1024) k_fps3(const float4* __restrict__ spos,
                                               const float4* __restrict__ posf4,
                                               const float* __restrict__ pos,
                                               int* __restrict__ ids) {
    const int tid = threadIdx.x, lane = tid & 63, wid = tid >> 6;
    const int base = tid * PTT;
    __shared__ u64 keys[1024];
    __shared__ float cs[4];
    float md[PTT];
    float bxn = 3.4e38f, byn = 3.4e38f, bzn = 3.4e38f;
    float bxm = -3.4e38f, bym = -3.4e38f, bzm = -3.4e38f;
    #pragma unroll
    for (int i = 0; i < PTT; ++i) {
        md[i] = 1e10f;
        float4 s = spos[base + i];
        bxn = fminf(bxn, s.x); bxm = fmaxf(bxm, s.x);
        byn = fminf(byn, s.y); bym = fmaxf(bym, s.y);
        bzn = fminf(bzn, s.z); bzm = fmaxf(bzm, s.z);
    }
    float tmax = 1e10f;              // md[] all start at BIG -> force first scan
    float cx = pos[0], cy = pos[1], cz = pos[2];   // seed: original point 0
    if (tid == 0) ids[0] = 0;
    for (int it = 0; it < NITER; ++it) {
        // Phase A: conservative skip + branch-free scan
        float ddx = fmaxf(0.0f, fmaxf(bxn - cx, cx - bxm));
        float ddy = fmaxf(0.0f, fmaxf(byn - cy, cy - bym));
        float ddz = fmaxf(0.0f, fmaxf(bzn - cz, cz - bzm));
        float lb = (ddx * ddx + ddy * ddy + ddz * ddz) * 0.999999f;
        if (lb < tmax) {
            u64 nk = 0ull;
            #pragma unroll
            for (int i = 0; i < PTT; ++i) {
                float4 s = spos[base + i];
                // exact np arithmetic: rn sub/mul/add, no contraction
                float dx = __fsub_rn(s.x, cx), dy = __fsub_rn(s.y, cy), dz = __fsub_rn(s.z, cz);
                float d = __fadd_rn(__fadd_rn(__fmul_rn(dx, dx), __fmul_rn(dy, dy)),
                                    __fmul_rn(dz, dz));
                float m = fminf(md[i], d);
                md[i] = m;
                u64 k = ((u64)__float_as_uint(m) << 32) |
                        (u64)(0xFFFFu - (u32)__float_as_uint(s.w));
                if (k > nk) nk = k;
            }
            tmax = __uint_as_float((u32)(nk >> 32));
            keys[tid] = nk;
        }
        __syncthreads();
        // Phase B: wave 0 only
        if (wid == 0) {
            u64 v = 0ull;
            #pragma unroll
            for (int j = 0; j < 16; ++j) {
                u64 k = keys[j * 64 + lane];
                if (k > v) v = k;
            }
            #pragma unroll
            for (int o = 32; o >= 1; o >>= 1) {
                u64 ot = __shfl_xor(v, o);
                if (ot > v) v = ot;
            }
            if (lane == 0) {
                int orig = 0xFFFF - (int)(v & 0xFFFFull);
                ids[it + 1] = orig;
                float4 c = posf4[orig];
                cs[0] = c.x; cs[1] = c.y; cs[2] = c.z;
            }
        }
        __syncthreads();
        cx = cs[0]; cy = cs[1]; cz = cs[2];
    }
}

// sub_pos + sub_batch outputs
__global__ void k_subs(const float* __restrict__ pos, const int* __restrict__ batch,
                       const int* __restrict__ ids, float* __restrict__ out) {
    int m = blockIdx.x * blockDim.x + threadIdx.x;
    if (m < MCL) {
        int id = ids[m];
        out[OUT_POS + m * 3 + 0] = pos[id * 3 + 0];
        out[OUT_POS + m * 3 + 1] = pos[id * 3 + 1];
        out[OUT_POS + m * 3 + 2] = pos[id * 3 + 2];
        out[OUT_BATCH + m] = (float)batch[id];  // zeros in this problem
    }
}

__device__ __forceinline__ u32 f2sort(float d) {
    u32 u = __float_as_uint(d);
    return (u & 0x80000000u) ? ~u : (u | 0x80000000u);
}

// per-(query-block, chunk) partial top-8 by (d, idx) lex key
__global__ void __launch_bounds__(256) k_knn(const float4* __restrict__ posf4,
                                             const int* __restrict__ ids,
                                             u64* __restrict__ cand) {
    __shared__ float4 tile[KTILE];
    const int bid = blockIdx.x, tid = threadIdx.x;
    const int qb = bid % QBLK, chunk = bid / QBLK;
    const int q = qb * 256 + tid;
    const bool act = q < MCL;
    float qx = 0.f, qy = 0.f, qz = 0.f, qq = 0.f;
    if (act) { float4 p = posf4[ids[q]]; qx = p.x; qy = p.y; qz = p.z; qq = p.w; }
    u64 r[8];
    #pragma unroll
    for (int j = 0; j < 8; ++j) r[j] = ~0ull;
    const int base0 = chunk * CPTS;
    for (int t = 0; t < NTILE; ++t) {
        __syncthreads();
        if (tid < KTILE) tile[tid] = posf4[base0 + t * KTILE + tid];
        __syncthreads();
        if (act) {
            for (int p = 0; p < KTILE; ++p) {
                float4 f = tile[p];
                // BLAS sgemm K=3 rounding: c=rn(qx*px); c=fma(qy,py,c); c=fma(qz,pz,c)
                float c = __fmul_rn(qx, f.x);
                c = fmaf(qy, f.y, c);
                c = fmaf(qz, f.z, c);
                float d = __fadd_rn(__fsub_rn(qq, __fmul_rn(2.0f, c)), f.w);
                u64 key = ((u64)f2sort(d) << 32) | (u32)(base0 + t * KTILE + p);
                if (key < r[7]) {
                    r[7] = key;
                    #pragma unroll
                    for (int jj = 7; jj >= 1; --jj) {
                        if (r[jj] < r[jj - 1]) { u64 tk = r[jj]; r[jj] = r[jj - 1]; r[jj - 1] = tk; }
                    }
                }
            }
        }
    }
    if (act) {
        #pragma unroll
        for (int j = 0; j < 8; ++j) cand[(size_t)q * 32 + chunk * 8 + j] = r[j];
    }
}

__global__ void k_merge(const u64* __restrict__ cand, int* __restrict__ col) {
    int q = blockIdx.x * blockDim.x + threadIdx.x;
    if (q >= MCL) return;
    u64 r[8];
    #pragma unroll
    for (int j = 0; j < 8; ++j) r[j] = ~0ull;
    for (int k = 0; k < 32; ++k) {
        u64 key = cand[(size_t)q * 32 + k];
        if (key < r[7]) {
            r[7] = key;
            #pragma unroll
            for (int jj = 7; jj >= 1; --jj) {
                if (r[jj] < r[jj - 1]) { u64 tk = r[jj]; r[jj] = r[jj - 1]; r[jj - 1] = tk; }
            }
        }
    }
    #pragma unroll
    for (int j = 0; j < 8; ++j) col[q * 8 + j] = (int)(r[j] & 0xFFFFFFFFull);
}

// Linear(64->128) per-channel sum / sumsq partials (64 rows per block)
__global__ void __launch_bounds__(256) k_linstats(const float* __restrict__ x,
                                                  const float* __restrict__ w,
                                                  const float* __restrict__ b,
                                                  float* __restrict__ psum,
                                                  float* __restrict__ psq) {
    __shared__ float xs[64 * 65];
    __shared__ float ws[128 * 65];
    const int bid = blockIdx.x, tid = threadIdx.x;
    const int row0 = bid * 64;
    for (int idx = tid; idx < 64 * 64; idx += 256) {
        int r = idx >> 6, j = idx & 63;
        int gr = row0 + r;
        xs[r * 65 + j] = (gr < NPTS) ? x[gr * 64 + j] : 0.0f;
    }
    for (int idx = tid; idx < 128 * 64; idx += 256) {
        int c = idx >> 6, j = idx & 63;
        ws[c * 65 + j] = w[idx];
    }
    __syncthreads();
    const int ch = tid & 127, grp = tid >> 7;
    const float lb = b[ch];
    float s = 0.f, sq = 0.f;
    for (int rr = 0; rr < 32; ++rr) {
        int r = grp * 32 + rr;
        float acc = lb;
        #pragma unroll 8
        for (int j = 0; j < 64; ++j) acc = fmaf(xs[r * 65 + j], ws[ch * 65 + j], acc);
        if (row0 + r < NPTS) { s += acc; sq = fmaf(acc, acc, sq); }
    }
    __syncthreads();
    float* red = xs;  // reuse
    red[grp * 128 + ch] = s;
    red[256 + grp * 128 + ch] = sq;
    __syncthreads();
    if (grp == 0) {
        psum[bid * 128 + ch] = red[ch] + red[128 + ch];
        psq[bid * 128 + ch] = red[256 + ch] + red[256 + 128 + ch];
    }
}

// mean/var -> per-channel affine (alpha, beta); folds GraphNorm
__global__ void k_finalize(const float* __restrict__ psum, const float* __restrict__ psq,
                           const float* __restrict__ gnw, const float* __restrict__ gnb,
                           const float* __restrict__ gms, float* __restrict__ ab) {
    int ch = threadIdx.x;  // 128 threads
    float s = 0.f, q = 0.f;
    for (int bk = 0; bk < RB; ++bk) { s += psum[bk * 128 + ch]; q += psq[bk * 128 + ch]; }
    float m = s / (float)NPTS;
    float e2 = q / (float)NPTS;
    float msc = gms[ch];
    float mm = msc * m;
    float var = e2 - 2.0f * mm * m + mm * mm;
    float inv = rsqrtf(var + 1e-5f);
    float a = inv * gnw[ch];
    ab[ch] = a;
    ab[128 + ch] = gnb[ch] - mm * a;
}

// recompute h rows for the 8 neighbors, max/min, affine+relu, write out
__global__ void __launch_bounds__(128) k_gather(const float* __restrict__ x,
                                                const float* __restrict__ w,
                                                const float* __restrict__ b,
                                                const int* __restrict__ col,
                                                const float* __restrict__ ab,
                                                float* __restrict__ out) {
    __shared__ float xs[8 * 64];
    __shared__ float ws[128 * 65];
    __shared__ int cl[8];
    const int m = blockIdx.x, tid = threadIdx.x;
    if (tid < 8) cl[tid] = col[m * 8 + tid];
    __syncthreads();
    for (int idx = tid; idx < 512; idx += 128) {
        int r = idx >> 6, j = idx & 63;
        xs[idx] = x[cl[r] * 64 + j];
    }
    for (int idx = tid; idx < 128 * 64; idx += 128) {
        int c = idx >> 6, j = idx & 63;
        ws[c * 65 + j] = w[idx];
    }
    __syncthreads();
    const int ch = tid;
    const float lb = b[ch];
    float hmax = -3.402823466e38f, hmin = 3.402823466e38f;
    #pragma unroll
    for (int r = 0; r < 8; ++r) {
        float acc = lb;
        #pragma unroll 8
        for (int j = 0; j < 64; ++j) acc = fmaf(xs[r * 64 + j], ws[ch * 65 + j], acc);
        hmax = fmaxf(hmax, acc);
        hmin = fminf(hmin, acc);
    }
    float a = ab[ch], be = ab[128 + ch];
    float v = (a >= 0.0f) ? hmax : hmin;   // max/affine commute per sign
    out[m * OUTC + ch] = fmaxf(0.0f, fmaf(a, v, be));
}

extern "C" void kernel_launch(void* const* d_in, const int* in_sizes, int n_in,
                              void* d_out, int out_size, void* d_ws, size_t ws_size,
                              hipStream_t stream) {
    const float* x     = (const float*)d_in[0];
    const float* pos   = (const float*)d_in[1];
    const int*   batch = (const int*)d_in[2];
    const float* lin_w = (const float*)d_in[3];
    const float* lin_b = (const float*)d_in[4];
    const float* gnw   = (const float*)d_in[5];
    const float* gnb   = (const float*)d_in[6];
    const float* gms   = (const float*)d_in[7];
    float* out = (float*)d_out;

    if (ws_size < (size_t)WS_TOTAL) return;  // fail loudly via wrong output

    char* ws = (char*)d_ws;
    int*    ids   = (int*)(ws + WS_IDS);
    float*  bbox  = (float*)(ws + WS_BBOX);
    float4* posf4 = (float4*)(ws + WS_POSF4);
    float4* spos  = (float4*)(ws + WS_SPOS);
    u64*    cand  = (u64*)(ws + WS_CAND);
    int*    col   = (int*)(ws + WS_COL);
    float*  psum  = (float*)(ws + WS_PSUM);
    float*  psq   = (float*)(ws + WS_PSQ);
    float*  ab    = (float*)(ws + WS_AB);

    k_prep<<<196, 256, 0, stream>>>(pos, posf4);
    k_bbox<<<1, 1024, 0, stream>>>(pos, bbox);
    k_sort<<<1, 1024, 0, stream>>>(pos, bbox, spos);
    k_fps3<<<1, 1024, 0, stream>>>(spos, posf4, pos, ids);
    k_subs<<<QBLK, 256, 0, stream>>>(pos, batch, ids, out);
    k_knn<<<QBLK * KCH, 256, 0, stream>>>(posf4, ids, cand);
    k_merge<<<QBLK, 256, 0, stream>>>(cand, col);
    k_linstats<<<RB, 256, 0, stream>>>(x, lin_w, lin_b, psum, psq);
    k_finalize<<<1, 128, 0, stream>>>(psum, psq, gnw, gnb, gms, ab);
    k_gather<<<MCL, 128, 0, stream>>>(x, lin_w, lin_b, col, ab, out);
}